// Round 11
// baseline (367.945 us; speedup 1.0000x reference)
//
#include <hip/hip_runtime.h>
#include <math.h>

// Problem constants: B=4, S=1024, D=512, H=8
constexpr int B_ = 4, S_ = 1024, D_ = 512, H_ = 8;
constexpr float EPS_ = 1e-6f;
constexpr float MAXT = 1.0f - 1e-5f;

typedef __attribute__((ext_vector_type(8))) short bf16x8;
typedef __attribute__((ext_vector_type(4))) float f32x4;

__device__ __forceinline__ ushort f2b(float f) {
    unsigned u = __float_as_uint(f);
    unsigned r = u + 0x7fffu + ((u >> 16) & 1u);
    return (ushort)(r >> 16);
}
__device__ __forceinline__ float b2f(ushort h) {
    return __uint_as_float(((unsigned)h) << 16);
}

__device__ __forceinline__ void async16(const ushort* g, ushort* l) {
    __builtin_amdgcn_global_load_lds(
        (const __attribute__((address_space(1))) unsigned int*)g,
        (__attribute__((address_space(3))) unsigned int*)l, 16, 0, 0);
}

// ---------------- block reductions (blockDim.x == 256) ----------------
__device__ __forceinline__ float blk_reduce_sum(float v, float* sm) {
    for (int o = 32; o > 0; o >>= 1) v += __shfl_down(v, o, 64);
    int lane = threadIdx.x & 63, wid = threadIdx.x >> 6;
    if (lane == 0) sm[wid] = v;
    __syncthreads();
    if (threadIdx.x == 0) sm[0] = sm[0] + sm[1] + sm[2] + sm[3];
    __syncthreads();
    float r = sm[0];
    __syncthreads();
    return r;
}

// ---------------- MFMA NT-GEMM core 128x128, double-buffered, 4 blocks/CU ----------------
// acc[4][4] f32x4 = 64 AGPRs; total ~100 VGPR -> fits launch_bounds(256,4) cap of 128.
// (m103: 128-square tile is the measured-best shape: 912 TF vs 823/792 for wider tiles.)
// LDS: 2 buffers x (A 128x32 + B 128x32) bf16 = 32 KB -> 4 blocks/CU = 16 waves/CU.
constexpr int GC_ABUF = 128 * 32;
constexpr int GC_BUF = 256 * 32;
constexpr int GC_SH = GC_BUF * 2;  // 32 KB

__device__ __forceinline__ void gemm_core128(const ushort* __restrict__ A,
                                             const ushort* __restrict__ B,
                                             int lda, int ldb, int K, int m0, int n0,
                                             ushort* __restrict__ sh, f32x4 acc[4][4]) {
    const int tid = threadIdx.x;
    const int w = tid >> 6, lane = tid & 63;
    const int wm = w >> 1, wn = w & 1;
    const int quad = lane >> 4, lx = lane & 15;
    const int rr = lane >> 2, c = lane & 3;

    // staging: wave w stages rows [w*32, w*32+32) of A and B, 2 issues each
    const ushort* aP[2];
    const ushort* bP[2];
    int aOff[2], bOff[2];
#pragma unroll
    for (int i = 0; i < 2; i++) {
        int r = w * 32 + i * 16 + rr;
        int q = c ^ ((r >> 1) & 3);
        aP[i] = A + (size_t)(m0 + r) * lda + q * 8;
        bP[i] = B + (size_t)(n0 + r) * ldb + q * 8;
        aOff[i] = (w * 32 + i * 16) * 32;
        bOff[i] = GC_ABUF + (w * 32 + i * 16) * 32;
    }

    int raOff[4], rbOff[4];
#pragma unroll
    for (int i = 0; i < 4; i++) {
        int ra = wm * 64 + i * 16 + lx;
        raOff[i] = ra * 32 + (quad ^ ((ra >> 1) & 3)) * 8;
        int rb = wn * 64 + i * 16 + lx;
        rbOff[i] = GC_ABUF + rb * 32 + (quad ^ ((rb >> 1) & 3)) * 8;
    }
#pragma unroll
    for (int i = 0; i < 4; i++)
#pragma unroll
        for (int j = 0; j < 4; j++) acc[i][j] = (f32x4)(0.0f);

    // prologue: step 0 into buffer 0
#pragma unroll
    for (int i = 0; i < 2; i++) async16(aP[i], sh + aOff[i]);
#pragma unroll
    for (int i = 0; i < 2; i++) async16(bP[i], sh + bOff[i]);

    const int nsteps = K >> 5;
    for (int s = 0; s < nsteps; s++) {
        ushort* cur = sh + (s & 1) * GC_BUF;
        if (s + 1 < nsteps) {
            ushort* nxt = sh + ((s + 1) & 1) * GC_BUF;
            int k0 = (s + 1) << 5;
#pragma unroll
            for (int i = 0; i < 2; i++) async16(aP[i] + k0, nxt + aOff[i]);
#pragma unroll
            for (int i = 0; i < 2; i++) async16(bP[i] + k0, nxt + bOff[i]);
            asm volatile("s_waitcnt vmcnt(4)" ::: "memory");
        } else {
            asm volatile("s_waitcnt vmcnt(0)" ::: "memory");
        }
        asm volatile("s_barrier" ::: "memory");
        bf16x8 af[4], bfr[4];
#pragma unroll
        for (int i = 0; i < 4; i++) af[i] = *(const bf16x8*)(cur + raOff[i]);
#pragma unroll
        for (int j = 0; j < 4; j++) bfr[j] = *(const bf16x8*)(cur + rbOff[j]);
#pragma unroll
        for (int i = 0; i < 4; i++)
#pragma unroll
            for (int j = 0; j < 4; j++)
                acc[i][j] = __builtin_amdgcn_mfma_f32_16x16x32_bf16(af[i], bfr[j], acc[i][j], 0, 0, 0);
        asm volatile("s_waitcnt lgkmcnt(0)" ::: "memory");
        asm volatile("s_barrier" ::: "memory");
    }
}

// ---------------- fused q/k/v projection + per-row |y|^2 atomics ----------------
__global__ __launch_bounds__(256, 4) void k_gemm_proj_all(const ushort* __restrict__ tq,
                                                          const ushort* __restrict__ tk,
                                                          const ushort* __restrict__ tv,
                                                          const ushort* __restrict__ WqT,
                                                          const ushort* __restrict__ WkT,
                                                          const ushort* __restrict__ WvT,
                                                          const float* __restrict__ bq,
                                                          const float* __restrict__ bk,
                                                          const float* __restrict__ bv,
                                                          ushort* __restrict__ yq,
                                                          ushort* __restrict__ yk,
                                                          ushort* __restrict__ yv,
                                                          float* __restrict__ ssq,
                                                          float* __restrict__ ssk,
                                                          float* __restrict__ ssv) {
    __shared__ ushort sh[GC_SH];
    int z = blockIdx.z;
    const ushort* A;
    const ushort* BT;
    const float* bias;
    ushort* C;
    float* SS;
    int remap = 0, h = 0;
    if (z == 0) { A = tk; BT = WkT; bias = bk; C = yk; SS = ssk; }
    else if (z == 1) { A = tv; BT = WvT; bias = bv; C = yv; SS = ssv; }
    else {
        h = z - 2;
        A = tq; BT = WqT + (size_t)h * 512 * 512; bias = bq + (size_t)h * 512;
        C = yq; SS = ssq; remap = 1;
    }
    f32x4 acc[4][4];
    int m0 = blockIdx.y * 128, n0 = blockIdx.x * 128;
    gemm_core128(A, BT, 512, 512, 512, m0, n0, sh, acc);
    int tid = threadIdx.x, w = tid >> 6, lane = tid & 63;
    int wm = w >> 1, wn = w & 1, quad = lane >> 4, lx = lane & 15;
#pragma unroll
    for (int i = 0; i < 4; i++)
#pragma unroll
        for (int reg = 0; reg < 4; reg++) {
            int m = m0 + wm * 64 + i * 16 + quad * 4 + reg;
            size_t orow = remap ? (size_t)((m >> 10) * H_ + h) * S_ + (m & 1023) : (size_t)m;
            float ssum = 0.0f;
#pragma unroll
            for (int j = 0; j < 4; j++) {
                int n = n0 + wn * 64 + j * 16 + lx;
                ushort hb = f2b(acc[i][j][reg] + bias[n]);
                C[orow * 512 + n] = hb;
                float yv_ = b2f(hb);
                ssum += yv_ * yv_;
            }
            for (int o = 8; o; o >>= 1) ssum += __shfl_xor(ssum, o, 64);
            if (lx == 0) atomicAdd(&SS[orow], ssum);
        }
}

// ---------------- merged post-proj: yv transpose (lin<2048) + ball factors (lin>=2048) ----------------
__global__ __launch_bounds__(256) void k_post_proj(const ushort* __restrict__ yv,
                                                   ushort* __restrict__ yvT,
                                                   const float* __restrict__ ssq,
                                                   const float* __restrict__ ssk,
                                                   const float* __restrict__ ssv,
                                                   float* __restrict__ fq,
                                                   float* __restrict__ qn2,
                                                   float* __restrict__ fk,
                                                   float* __restrict__ kn2,
                                                   float* __restrict__ cv,
                                                   float* __restrict__ dsc) {
    int lin = blockIdx.x;
    if (lin < 2048) {
        __shared__ ushort t[32][34];
        int z = lin >> 9, rem = lin & 511;
        int by = rem >> 4, bx = rem & 15;
        const ushort* in = yv + (size_t)z * 1024 * 512;
        ushort* out = yvT + (size_t)z * 512 * 1024;
        int c0 = bx * 32, r0 = by * 32;
        int tx = threadIdx.x & 31, ty = threadIdx.x >> 5;
        for (int rr = ty; rr < 32; rr += 8) t[rr][tx] = in[(size_t)(r0 + rr) * 512 + c0 + tx];
        __syncthreads();
        for (int rr = ty; rr < 32; rr += 8)
            out[(size_t)(c0 + rr) * 1024 + r0 + tx] = t[tx][rr];
        return;
    }
    int idx = (lin - 2048) * 256 + threadIdx.x;
    if (idx >= 40960) return;
    float ss;
    if (idx < 32768) ss = ssq[idx];
    else if (idx < 36864) ss = ssk[idx - 32768];
    else ss = ssv[idx - 36864];
    float n = sqrtf(fmaxf(ss, EPS_));
    float f = tanhf(n) / n;
    float bn2 = fminf(f * f * ss, MAXT);
    if (idx < 32768) {
        fq[idx] = f;
        qn2[idx] = bn2;
    } else if (idx < 36864) {
        fk[idx - 32768] = f;
        kn2[idx - 32768] = bn2;
    } else {
        int r = idx - 36864;
        float lam = 2.0f / (1.0f - bn2);
        float c = f * lam;
        cv[r] = c;
        dsc[r] = (lam - 1.0f) / c;
    }
}

// ---------------- score GEMM: dist -> E' = e*cv bf16, den atomic ----------------
__global__ __launch_bounds__(256, 4) void k_gemm_score(const ushort* __restrict__ Yq,
                                                       const ushort* __restrict__ Yk,
                                                       ushort* __restrict__ E,
                                                       float* __restrict__ den,
                                                       const float* __restrict__ fq,
                                                       const float* __restrict__ qn2,
                                                       const float* __restrict__ fk,
                                                       const float* __restrict__ kn2,
                                                       const float* __restrict__ cv,
                                                       const float* __restrict__ dsc,
                                                       const float* __restrict__ stau) {
    __shared__ ushort sh[GC_SH];
    int b = blockIdx.z;
    int m0 = blockIdx.y * 128, n0 = blockIdx.x * 128;
    const ushort* Aq = Yq + (size_t)b * 8192 * 512;
    const ushort* Bk = Yk + (size_t)b * 1024 * 512;
    E += (size_t)b * 8192 * 1024;
    den += (size_t)b * 8192;
    const float* fqb = fq + (size_t)b * 8192;
    const float* qn2b = qn2 + (size_t)b * 8192;
    const float* fkb = fk + (size_t)b * 1024;
    const float* kn2b = kn2 + (size_t)b * 1024;
    const float* cvb = cv + (size_t)b * 1024;
    const float* dscb = dsc + (size_t)b * 1024;

    f32x4 acc[4][4];
    gemm_core128(Aq, Bk, 512, 512, 512, m0, n0, sh, acc);
    float itau = expf(stau[0]);
    bool tau1 = (itau == 1.0f);
    int tid = threadIdx.x, w_ = tid >> 6, lane = tid & 63;
    int wm = w_ >> 1, wn = w_ & 1, quad = lane >> 4, lx = lane & 15;
    float fkv[4], kn2v[4], cvv[4], dscv[4], rk[4];
#pragma unroll
    for (int j = 0; j < 4; j++) {
        int n = n0 + wn * 64 + j * 16 + lx;
        fkv[j] = fkb[n];
        kn2v[j] = kn2b[n];
        rk[j] = __builtin_amdgcn_rcpf(1.0f - kn2v[j]);
        cvv[j] = cvb[n];
        dscv[j] = dscb[n];
    }
#pragma unroll
    for (int i = 0; i < 4; i++)
#pragma unroll
        for (int reg = 0; reg < 4; reg++) {
            int m = m0 + wm * 64 + i * 16 + quad * 4 + reg;
            float fqm = fqb[m];
            float q = qn2b[m];
            float rq2 = 2.0f * __builtin_amdgcn_rcpf(1.0f - q);
            float rsum = 0.0f;
#pragma unroll
            for (int j = 0; j < 4; j++) {
                float dot = fqm * fkv[j] * acc[i][j][reg];
                float sq = fmaxf(q + kn2v[j] - 2.0f * dot, 0.0f);
                float rr2 = fminf(rq2 * rk[j], 2e6f);
                float w = fmaxf(sq * rr2, 1e-7f);
                float root = __builtin_amdgcn_sqrtf(__builtin_fmaf(w, w, 2.0f * w));
                float t = 1.0f + w + root;
                float e = tau1 ? __builtin_amdgcn_rcpf(t)
                               : __builtin_amdgcn_exp2f(-itau * __builtin_amdgcn_logf(t));
                ushort eb = f2b(e * cvv[j]);
                int n = n0 + wn * 64 + j * 16 + lx;
                E[(size_t)m * 1024 + n] = eb;
                rsum += b2f(eb) * dscv[j];
            }
            for (int o = 8; o; o >>= 1) rsum += __shfl_xor(rsum, o, 64);
            if (lx == 0) atomicAdd(&den[m], rsum);
        }
}

// ---------------- attn x V GEMM: u = (E' @ yv^T)/den -> bf16 U + atomic ss ----------------
__global__ __launch_bounds__(256, 4) void k_gemm_attnv(const ushort* __restrict__ E,
                                                       const ushort* __restrict__ VT,
                                                       const float* __restrict__ den,
                                                       ushort* __restrict__ Ub,
                                                       float* __restrict__ ssU) {
    __shared__ ushort sh[GC_SH];
    int b = blockIdx.z;
    int m0 = blockIdx.y * 128, n0 = blockIdx.x * 128;
    E += (size_t)b * 8192 * 1024;
    VT += (size_t)b * 512 * 1024;
    den += (size_t)b * 8192;
    Ub += (size_t)b * 8192 * 512;
    ssU += (size_t)b * 8192;
    f32x4 acc[4][4];
    gemm_core128(E, VT, 1024, 1024, 1024, m0, n0, sh, acc);
    int tid = threadIdx.x, w = tid >> 6, lane = tid & 63;
    int wm = w >> 1, wn = w & 1, quad = lane >> 4, lx = lane & 15;
#pragma unroll
    for (int i = 0; i < 4; i++)
#pragma unroll
        for (int reg = 0; reg < 4; reg++) {
            int m = m0 + wm * 64 + i * 16 + quad * 4 + reg;
            float inv = __builtin_amdgcn_rcpf(fmaxf(den[m], EPS_));
            float ssum = 0.0f;
#pragma unroll
            for (int j = 0; j < 4; j++) {
                int n = n0 + wn * 64 + j * 16 + lx;
                float u = acc[i][j][reg] * inv;
                Ub[(size_t)m * 512 + n] = f2b(u);
                ssum += u * u;
            }
            for (int o = 8; o; o >>= 1) ssum += __shfl_xor(ssum, o, 64);
            if (lx == 0) atomicAdd(&ssU[m], ssum);
        }
}

// ---------------- output projection split-K over 8 head-chunks ----------------
__global__ __launch_bounds__(256, 4) void k_gemm_sk(const ushort* __restrict__ Ub,
                                                    const ushort* __restrict__ WoT,
                                                    float* __restrict__ Cp) {
    __shared__ ushort sh[GC_SH];
    int z = blockIdx.z;
    int m0 = blockIdx.y * 128, n0 = blockIdx.x * 128;
    int bb = m0 >> 10, s0 = m0 & 1023;
    const ushort* A = Ub + ((size_t)(bb * H_ + z) * S_ + s0) * 512;
    const ushort* BT = WoT + (size_t)z * 512;
    float* C = Cp + (size_t)z * 4096 * 512;
    f32x4 acc[4][4];
    gemm_core128(A, BT, 512, 4096, 512, 0, n0, sh, acc);
    int tid = threadIdx.x, w = tid >> 6, lane = tid & 63;
    int wm = w >> 1, wn = w & 1, quad = lane >> 4, lx = lane & 15;
#pragma unroll
    for (int i = 0; i < 4; i++)
#pragma unroll
        for (int reg = 0; reg < 4; reg++) {
            int m = m0 + wm * 64 + i * 16 + quad * 4 + reg;
#pragma unroll
            for (int j = 0; j < 4; j++) {
                int n = n0 + wn * 64 + j * 16 + lx;
                C[(size_t)m * 512 + n] = acc[i][j][reg];
            }
        }
}

// ---------------- final reduce + in-block hyper factors + expmap ----------------
__global__ __launch_bounds__(256) void k_final_reduce_expmap(const float* __restrict__ Cp,
                                                             const float* __restrict__ ssU,
                                                             const float* __restrict__ bo,
                                                             float* __restrict__ out) {
    __shared__ float sm[24];
    int r = blockIdx.x;
    int b = r >> 10, s = r & 1023;
    if (threadIdx.x < 8) {
        int h = threadIdx.x;
        float ss = ssU[(size_t)(b * H_ + h) * S_ + s];
        float n = sqrtf(fmaxf(ss, EPS_));
        float a = 0.5f * atanhf(fminf(n, MAXT));
        float f1 = tanhf(a) / n;
        float mss = f1 * f1 * ss;
        float nm = sqrtf(fmaxf(mss, EPS_));
        float f2 = atanhf(fminf(nm, MAXT)) / nm;
        float f12 = f1 * f2;
        sm[h] = f12;
        sm[8 + h] = f12 * f12 * ss;
    }
    __syncthreads();
    if (threadIdx.x == 0) {
        float sum = 0.0f;
#pragma unroll
        for (int h = 0; h < 8; h++) sum += sm[8 + h];
        float nc = sqrtf(fmaxf(sum, EPS_));
        float f3 = tanhf(nc) / nc;
        float css = f3 * f3 * sum;
        float nc2 = sqrtf(fmaxf(css, EPS_));
        float f4 = atanhf(fminf(nc2, MAXT)) / nc2;
        sm[16] = f3 * f4;
    }
    __syncthreads();
    float g = sm[16];
    float a8[8];
#pragma unroll
    for (int z = 0; z < 8; z++) a8[z] = sm[z] * g;
    float v0 = bo[threadIdx.x], v1 = bo[threadIdx.x + 256];
#pragma unroll
    for (int z = 0; z < 8; z++) {
        const float* row = Cp + ((size_t)z * 4096 + r) * 512;
        v0 += a8[z] * row[threadIdx.x];
        v1 += a8[z] * row[threadIdx.x + 256];
    }
    float ss = blk_reduce_sum(v0 * v0 + v1 * v1, sm + 17);
    float n = sqrtf(fmaxf(ss, EPS_));
    float f = tanhf(n) / n;
    float* o = out + (size_t)r * D_;
    o[threadIdx.x] = f * v0;
    o[threadIdx.x + 256] = f * v1;
}

// ---------------- logmap0 rows -> bf16 tangent ----------------
__global__ __launch_bounds__(256) void k_logmap_bf16(const float* __restrict__ q,
                                                     const float* __restrict__ k,
                                                     const float* __restrict__ v,
                                                     ushort* __restrict__ tq,
                                                     ushort* __restrict__ tk,
                                                     ushort* __restrict__ tv) {
    __shared__ float sm[8];
    const float* x = (blockIdx.y == 0) ? q : (blockIdx.y == 1) ? k : v;
    ushort* t = (blockIdx.y == 0) ? tq : (blockIdx.y == 1) ? tk : tv;
    int r = blockIdx.x;
    const float* xr = x + (size_t)r * D_;
    float v0 = xr[threadIdx.x], v1 = xr[threadIdx.x + 256];
    float ss = blk_reduce_sum(v0 * v0 + v1 * v1, sm);
    float n = sqrtf(fmaxf(ss, EPS_));
    float f = atanhf(fminf(n, MAXT)) / n;
    ushort* tr = t + (size_t)r * D_;
    tr[threadIdx.x] = f2b(f * v0);
    tr[threadIdx.x + 256] = f2b(f * v1);
}

// ---------------- ALL weight transposes (z: 0=Wk, 1=Wv, 2..9=Wq heads, 10..17=Wo slices) ----------------
__global__ __launch_bounds__(256) void k_transpose_all(const float* __restrict__ Wk,
                                                       const float* __restrict__ Wv,
                                                       const float* __restrict__ Wq,
                                                       const float* __restrict__ Wo,
                                                       ushort* __restrict__ WkT,
                                                       ushort* __restrict__ WvT,
                                                       ushort* __restrict__ WqT,
                                                       ushort* __restrict__ WoT) {
    __shared__ float t[32][33];
    int z = blockIdx.z;
    int c0 = blockIdx.x * 32, r0 = blockIdx.y * 32;
    int tx = threadIdx.x & 31, ty = threadIdx.x >> 5;
    if (z < 10) {
        const float* in;
        ushort* out;
        if (z == 0) { in = Wk; out = WkT; }
        else if (z == 1) { in = Wv; out = WvT; }
        else { in = Wq + (size_t)(z - 2) * 512 * 512; out = WqT + (size_t)(z - 2) * 512 * 512; }
        for (int rr = ty; rr < 32; rr += 8) t[rr][tx] = in[(size_t)(r0 + rr) * 512 + c0 + tx];
        __syncthreads();
        for (int rr = ty; rr < 32; rr += 8)
            out[(size_t)(c0 + rr) * 512 + r0 + tx] = f2b(t[tx][rr]);
    } else {
        int zz = z - 10;
        const float* in = Wo + (size_t)zz * 512 * 512;
        for (int rr = ty; rr < 32; rr += 8) t[rr][tx] = in[(size_t)(r0 + rr) * 512 + c0 + tx];
        __syncthreads();
        for (int rr = ty; rr < 32; rr += 8)
            WoT[(size_t)(c0 + rr) * 4096 + zz * 512 + r0 + tx] = f2b(t[tx][rr]);
    }
}

extern "C" void kernel_launch(void* const* d_in, const int* in_sizes, int n_in,
                              void* d_out, int out_size, void* d_ws, size_t ws_size,
                              hipStream_t stream) {
    (void)in_sizes; (void)n_in; (void)out_size; (void)ws_size;
    const float* query = (const float*)d_in[0];
    const float* key = (const float*)d_in[1];
    const float* value = (const float*)d_in[2];
    const float* Wq = (const float*)d_in[3];
    const float* bq = (const float*)d_in[4];
    const float* Wk = (const float*)d_in[5];
    const float* bk = (const float*)d_in[6];
    const float* Wv = (const float*)d_in[7];
    const float* bv = (const float*)d_in[8];
    const float* Wo = (const float*)d_in[9];
    const float* bo = (const float*)d_in[10];
    const float* stau = (const float*)d_in[11];
    float* out = (float*)d_out;

    char* p = (char*)d_ws;
    auto alloc = [&](size_t bytes) {
        char* r = p;
        p += (bytes + 255) & ~(size_t)255;
        return r;
    };
    ushort* tq = (ushort*)alloc((size_t)4096 * 512 * 2);
    ushort* tk = (ushort*)alloc((size_t)4096 * 512 * 2);
    ushort* tv = (ushort*)alloc((size_t)4096 * 512 * 2);
    ushort* WqT = (ushort*)alloc((size_t)8 * 512 * 512 * 2);
    ushort* WkT = (ushort*)alloc((size_t)512 * 512 * 2);
    ushort* WvT = (ushort*)alloc((size_t)512 * 512 * 2);
    ushort* WoT = (ushort*)alloc((size_t)4096 * 512 * 2);
    ushort* yq = (ushort*)alloc((size_t)32768 * 512 * 2);
    ushort* yk = (ushort*)alloc((size_t)4096 * 512 * 2);
    ushort* yv = (ushort*)alloc((size_t)4096 * 512 * 2);
    ushort* yvT = (ushort*)alloc((size_t)4 * 512 * 1024 * 2);
    ushort* Ub = (ushort*)alloc((size_t)32768 * 512 * 2);
    ushort* Sc = (ushort*)alloc((size_t)4 * 8192 * 1024 * 2);  // alias: Cp after attnv consumes E
    float* den = (float*)alloc(32768 * 4);
    float* ssU = (float*)alloc(32768 * 4);
    float* ssq = (float*)alloc(32768 * 4);
    float* ssk = (float*)alloc(4096 * 4);
    float* ssv = (float*)alloc(4096 * 4);
    float* fq = (float*)alloc(32768 * 4);
    float* qn2 = (float*)alloc(32768 * 4);
    float* fk = (float*)alloc(4096 * 4);
    float* kn2 = (float*)alloc(4096 * 4);
    float* cv = (float*)alloc(4096 * 4);
    float* dsc = (float*)alloc(4096 * 4);
    float* Cp = (float*)Sc;

    hipMemsetAsync(den, 0, (size_t)(32768 * 3 + 4096 * 2 + 192) * 4, stream);

    // 1. tangent inputs (bf16)
    k_logmap_bf16<<<dim3(4096, 3), 256, 0, stream>>>(query, key, value, tq, tk, tv);

    // 2. all weight transposes, one launch
    k_transpose_all<<<dim3(16, 16, 18), 256, 0, stream>>>(Wk, Wv, Wq, Wo, WkT, WvT, WqT, WoT);

    // 3. all projections + per-row |y|^2 atomics  (128-tiles: grid m doubled)
    k_gemm_proj_all<<<dim3(4, 32, 10), 256, 0, stream>>>(tq, tk, tv, WqT, WkT, WvT, bq, bk, bv,
                                                         yq, yk, yv, ssq, ssk, ssv);

    // 4. merged: yv transpose + ball factors
    k_post_proj<<<2208, 256, 0, stream>>>(yv, yvT, ssq, ssk, ssv, fq, qn2, fk, kn2, cv, dsc);

    // 5. attention (n-fastest grid mapping)
    k_gemm_score<<<dim3(8, 64, 4), 256, 0, stream>>>(yq, yk, Sc, den, fq, qn2, fk, kn2, cv, dsc,
                                                     stau);
    k_gemm_attnv<<<dim3(4, 64, 4), 256, 0, stream>>>(Sc, yvT, den, Ub, ssU);

    // 6. output projection split-K + fused factors/reduce/expmap
    k_gemm_sk<<<dim3(4, 32, 8), 256, 0, stream>>>(Ub, WoT, Cp);
    k_final_reduce_expmap<<<4096, 256, 0, stream>>>(Cp, ssU, bo, out);
}

// Round 13
// 349.741 us; speedup vs baseline: 1.0521x; 1.0521x over previous
//
#include <hip/hip_runtime.h>
#include <math.h>

// Problem constants: B=4, S=1024, D=512, H=8
constexpr int B_ = 4, S_ = 1024, D_ = 512, H_ = 8;
constexpr float EPS_ = 1e-6f;
constexpr float MAXT = 1.0f - 1e-5f;

typedef __attribute__((ext_vector_type(8))) short bf16x8;
typedef __attribute__((ext_vector_type(4))) float f32x4;

__device__ __forceinline__ ushort f2b(float f) {
    unsigned u = __float_as_uint(f);
    unsigned r = u + 0x7fffu + ((u >> 16) & 1u);
    return (ushort)(r >> 16);
}
__device__ __forceinline__ float b2f(ushort h) {
    return __uint_as_float(((unsigned)h) << 16);
}

__device__ __forceinline__ void async16(const ushort* g, ushort* l) {
    __builtin_amdgcn_global_load_lds(
        (const __attribute__((address_space(1))) unsigned int*)g,
        (__attribute__((address_space(3))) unsigned int*)l, 16, 0, 0);
}

// ---------------- block reductions (blockDim.x == 256) ----------------
__device__ __forceinline__ float blk_reduce_sum(float v, float* sm) {
    for (int o = 32; o > 0; o >>= 1) v += __shfl_down(v, o, 64);
    int lane = threadIdx.x & 63, wid = threadIdx.x >> 6;
    if (lane == 0) sm[wid] = v;
    __syncthreads();
    if (threadIdx.x == 0) sm[0] = sm[0] + sm[1] + sm[2] + sm[3];
    __syncthreads();
    float r = sm[0];
    __syncthreads();
    return r;
}

// ---------------- MFMA NT-GEMM core 256x128, double-buffered (R9-verified) ----------------
// Sweet spot (R8/R11 evidence): 2 blocks/CU, VGPR ~100, NO spill. Do not raise
// launch_bounds (R8: acc spill) or shrink tile for occupancy (R11: epilogue spill).
// GRID RULE: blockIdx.y spans M/256 exactly (R12 NaN: sk launched with y=32 on M=4096).
constexpr int GC_ABUF = 256 * 32;
constexpr int GC_BUF = (256 + 128) * 32;
constexpr int GC_SH = GC_BUF * 2;  // 48 KB

__device__ __forceinline__ void gemm_core256(const ushort* __restrict__ A,
                                             const ushort* __restrict__ B,
                                             int lda, int ldb, int K, int m0, int n0,
                                             ushort* __restrict__ sh, f32x4 acc[4][8]) {
    const int tid = threadIdx.x;
    const int w = tid >> 6, lane = tid & 63;
    const int quad = lane >> 4, lx = lane & 15;
    const int rr = lane >> 2, c = lane & 3;

    const ushort* aP[4];
    int aOff[4];
#pragma unroll
    for (int i = 0; i < 4; i++) {
        int r = w * 64 + i * 16 + rr;
        int q = c ^ ((r >> 1) & 3);
        aP[i] = A + (size_t)(m0 + r) * lda + q * 8;
        aOff[i] = (w * 64 + i * 16) * 32;
    }
    const ushort* bP[2];
    int bOff[2];
#pragma unroll
    for (int i = 0; i < 2; i++) {
        int r = w * 32 + i * 16 + rr;
        int q = c ^ ((r >> 1) & 3);
        bP[i] = B + (size_t)(n0 + r) * ldb + q * 8;
        bOff[i] = GC_ABUF + (w * 32 + i * 16) * 32;
    }

    int raOff[4], rbOff[8];
#pragma unroll
    for (int i = 0; i < 4; i++) {
        int ra = w * 64 + i * 16 + lx;
        raOff[i] = ra * 32 + (quad ^ ((ra >> 1) & 3)) * 8;
    }
#pragma unroll
    for (int j = 0; j < 8; j++) {
        int rb = j * 16 + lx;
        rbOff[j] = GC_ABUF + rb * 32 + (quad ^ ((rb >> 1) & 3)) * 8;
    }
#pragma unroll
    for (int i = 0; i < 4; i++)
#pragma unroll
        for (int j = 0; j < 8; j++) acc[i][j] = (f32x4)(0.0f);

#pragma unroll
    for (int i = 0; i < 4; i++) async16(aP[i], sh + aOff[i]);
#pragma unroll
    for (int i = 0; i < 2; i++) async16(bP[i], sh + bOff[i]);

    const int nsteps = K >> 5;
    for (int s = 0; s < nsteps; s++) {
        ushort* cur = sh + (s & 1) * GC_BUF;
        if (s + 1 < nsteps) {
            ushort* nxt = sh + ((s + 1) & 1) * GC_BUF;
            int k0 = (s + 1) << 5;
#pragma unroll
            for (int i = 0; i < 4; i++) async16(aP[i] + k0, nxt + aOff[i]);
#pragma unroll
            for (int i = 0; i < 2; i++) async16(bP[i] + k0, nxt + bOff[i]);
            asm volatile("s_waitcnt vmcnt(6)" ::: "memory");
        } else {
            asm volatile("s_waitcnt vmcnt(0)" ::: "memory");
        }
        asm volatile("s_barrier" ::: "memory");
        bf16x8 af[4], bfr[8];
#pragma unroll
        for (int i = 0; i < 4; i++) af[i] = *(const bf16x8*)(cur + raOff[i]);
#pragma unroll
        for (int j = 0; j < 8; j++) bfr[j] = *(const bf16x8*)(cur + rbOff[j]);
#pragma unroll
        for (int i = 0; i < 4; i++)
#pragma unroll
            for (int j = 0; j < 8; j++)
                acc[i][j] = __builtin_amdgcn_mfma_f32_16x16x32_bf16(af[i], bfr[j], acc[i][j], 0, 0, 0);
        asm volatile("s_waitcnt lgkmcnt(0)" ::: "memory");
        asm volatile("s_barrier" ::: "memory");
    }
}

// ---------------- fused q/k/v projection + per-row |y|^2 atomics ----------------
__global__ __launch_bounds__(256, 2) void k_gemm_proj_all(const ushort* __restrict__ tq,
                                                          const ushort* __restrict__ tk,
                                                          const ushort* __restrict__ tv,
                                                          const ushort* __restrict__ WqT,
                                                          const ushort* __restrict__ WkT,
                                                          const ushort* __restrict__ WvT,
                                                          const float* __restrict__ bq,
                                                          const float* __restrict__ bk,
                                                          const float* __restrict__ bv,
                                                          ushort* __restrict__ yq,
                                                          ushort* __restrict__ yk,
                                                          ushort* __restrict__ yv,
                                                          float* __restrict__ ssq,
                                                          float* __restrict__ ssk,
                                                          float* __restrict__ ssv) {
    __shared__ ushort sh[GC_SH];
    int z = blockIdx.z;
    const ushort* A;
    const ushort* BT;
    const float* bias;
    ushort* C;
    float* SS;
    int remap = 0, h = 0;
    if (z == 0) { A = tk; BT = WkT; bias = bk; C = yk; SS = ssk; }
    else if (z == 1) { A = tv; BT = WvT; bias = bv; C = yv; SS = ssv; }
    else {
        h = z - 2;
        A = tq; BT = WqT + (size_t)h * 512 * 512; bias = bq + (size_t)h * 512;
        C = yq; SS = ssq; remap = 1;
    }
    f32x4 acc[4][8];
    int m0 = blockIdx.y * 256, n0 = blockIdx.x * 128;
    gemm_core256(A, BT, 512, 512, 512, m0, n0, sh, acc);
    int tid = threadIdx.x, w = tid >> 6, lane = tid & 63;
    int quad = lane >> 4, lx = lane & 15;
#pragma unroll
    for (int i = 0; i < 4; i++)
#pragma unroll
        for (int reg = 0; reg < 4; reg++) {
            int m = m0 + w * 64 + i * 16 + quad * 4 + reg;
            size_t orow = remap ? (size_t)((m >> 10) * H_ + h) * S_ + (m & 1023) : (size_t)m;
            float ssum = 0.0f;
#pragma unroll
            for (int j = 0; j < 8; j++) {
                int n = n0 + j * 16 + lx;
                ushort hb = f2b(acc[i][j][reg] + bias[n]);
                C[orow * 512 + n] = hb;
                float yv_ = b2f(hb);
                ssum += yv_ * yv_;
            }
            for (int o = 8; o; o >>= 1) ssum += __shfl_xor(ssum, o, 64);
            if (lx == 0) atomicAdd(&SS[orow], ssum);
        }
}

// ---------------- merged post-proj: yv transpose (lin<2048) + ball factors (lin>=2048) ----------------
__global__ __launch_bounds__(256) void k_post_proj(const ushort* __restrict__ yv,
                                                   ushort* __restrict__ yvT,
                                                   const float* __restrict__ ssq,
                                                   const float* __restrict__ ssk,
                                                   const float* __restrict__ ssv,
                                                   float* __restrict__ fq,
                                                   float* __restrict__ qn2,
                                                   float* __restrict__ fk,
                                                   float* __restrict__ kn2,
                                                   float* __restrict__ cv,
                                                   float* __restrict__ dsc) {
    int lin = blockIdx.x;
    if (lin < 2048) {
        __shared__ ushort t[32][34];
        int z = lin >> 9, rem = lin & 511;
        int by = rem >> 4, bx = rem & 15;
        const ushort* in = yv + (size_t)z * 1024 * 512;
        ushort* out = yvT + (size_t)z * 512 * 1024;
        int c0 = bx * 32, r0 = by * 32;
        int tx = threadIdx.x & 31, ty = threadIdx.x >> 5;
        for (int rr = ty; rr < 32; rr += 8) t[rr][tx] = in[(size_t)(r0 + rr) * 512 + c0 + tx];
        __syncthreads();
        for (int rr = ty; rr < 32; rr += 8)
            out[(size_t)(c0 + rr) * 1024 + r0 + tx] = t[tx][rr];
        return;
    }
    int idx = (lin - 2048) * 256 + threadIdx.x;
    if (idx >= 40960) return;
    float ss;
    if (idx < 32768) ss = ssq[idx];
    else if (idx < 36864) ss = ssk[idx - 32768];
    else ss = ssv[idx - 36864];
    float n = sqrtf(fmaxf(ss, EPS_));
    float f = tanhf(n) / n;
    float bn2 = fminf(f * f * ss, MAXT);
    if (idx < 32768) {
        fq[idx] = f;
        qn2[idx] = bn2;
    } else if (idx < 36864) {
        fk[idx - 32768] = f;
        kn2[idx - 32768] = bn2;
    } else {
        int r = idx - 36864;
        float lam = 2.0f / (1.0f - bn2);
        float c = f * lam;
        cv[r] = c;
        dsc[r] = (lam - 1.0f) / c;
    }
}

// ---------------- score GEMM: dist -> E' = e*cv bf16, den atomic ----------------
__global__ __launch_bounds__(256, 2) void k_gemm_score(const ushort* __restrict__ Yq,
                                                       const ushort* __restrict__ Yk,
                                                       ushort* __restrict__ E,
                                                       float* __restrict__ den,
                                                       const float* __restrict__ fq,
                                                       const float* __restrict__ qn2,
                                                       const float* __restrict__ fk,
                                                       const float* __restrict__ kn2,
                                                       const float* __restrict__ cv,
                                                       const float* __restrict__ dsc,
                                                       const float* __restrict__ stau) {
    __shared__ ushort sh[GC_SH];
    int b = blockIdx.z;
    int m0 = blockIdx.y * 256, n0 = blockIdx.x * 128;
    const ushort* Aq = Yq + (size_t)b * 8192 * 512;
    const ushort* Bk = Yk + (size_t)b * 1024 * 512;
    E += (size_t)b * 8192 * 1024;
    den += (size_t)b * 8192;
    const float* fqb = fq + (size_t)b * 8192;
    const float* qn2b = qn2 + (size_t)b * 8192;
    const float* fkb = fk + (size_t)b * 1024;
    const float* kn2b = kn2 + (size_t)b * 1024;
    const float* cvb = cv + (size_t)b * 1024;
    const float* dscb = dsc + (size_t)b * 1024;

    f32x4 acc[4][8];
    gemm_core256(Aq, Bk, 512, 512, 512, m0, n0, sh, acc);
    float itau = expf(stau[0]);
    bool tau1 = (itau == 1.0f);
    int tid = threadIdx.x, w_ = tid >> 6, lane = tid & 63;
    int quad = lane >> 4, lx = lane & 15;
    float fkv[8], kn2v[8], cvv[8], dscv[8], rk[8];
#pragma unroll
    for (int j = 0; j < 8; j++) {
        int n = n0 + j * 16 + lx;
        fkv[j] = fkb[n];
        kn2v[j] = kn2b[n];
        rk[j] = __builtin_amdgcn_rcpf(1.0f - kn2v[j]);
        cvv[j] = cvb[n];
        dscv[j] = dscb[n];
    }
#pragma unroll
    for (int i = 0; i < 4; i++)
#pragma unroll
        for (int reg = 0; reg < 4; reg++) {
            int m = m0 + w_ * 64 + i * 16 + quad * 4 + reg;
            float fqm = fqb[m];
            float q = qn2b[m];
            float rq2 = 2.0f * __builtin_amdgcn_rcpf(1.0f - q);
            float rsum = 0.0f;
#pragma unroll
            for (int j = 0; j < 8; j++) {
                float dot = fqm * fkv[j] * acc[i][j][reg];
                float sq = fmaxf(q + kn2v[j] - 2.0f * dot, 0.0f);
                float rr2 = fminf(rq2 * rk[j], 2e6f);
                float w = fmaxf(sq * rr2, 1e-7f);
                float root = __builtin_amdgcn_sqrtf(__builtin_fmaf(w, w, 2.0f * w));
                float t = 1.0f + w + root;
                float e = tau1 ? __builtin_amdgcn_rcpf(t)
                               : __builtin_amdgcn_exp2f(-itau * __builtin_amdgcn_logf(t));
                ushort eb = f2b(e * cvv[j]);
                int n = n0 + j * 16 + lx;
                E[(size_t)m * 1024 + n] = eb;
                rsum += b2f(eb) * dscv[j];
            }
            for (int o = 8; o; o >>= 1) rsum += __shfl_xor(rsum, o, 64);
            if (lx == 0) atomicAdd(&den[m], rsum);
        }
}

// ---------------- attn x V GEMM: u = (E' @ yv^T)/den -> bf16 U + atomic ss ----------------
__global__ __launch_bounds__(256, 2) void k_gemm_attnv(const ushort* __restrict__ E,
                                                       const ushort* __restrict__ VT,
                                                       const float* __restrict__ den,
                                                       ushort* __restrict__ Ub,
                                                       float* __restrict__ ssU) {
    __shared__ ushort sh[GC_SH];
    int b = blockIdx.z;
    int m0 = blockIdx.y * 256, n0 = blockIdx.x * 128;
    E += (size_t)b * 8192 * 1024;
    VT += (size_t)b * 512 * 1024;
    den += (size_t)b * 8192;
    Ub += (size_t)b * 8192 * 512;
    ssU += (size_t)b * 8192;
    f32x4 acc[4][8];
    gemm_core256(E, VT, 1024, 1024, 1024, m0, n0, sh, acc);
    int tid = threadIdx.x, w = tid >> 6, lane = tid & 63;
    int quad = lane >> 4, lx = lane & 15;
#pragma unroll
    for (int i = 0; i < 4; i++)
#pragma unroll
        for (int reg = 0; reg < 4; reg++) {
            int m = m0 + w * 64 + i * 16 + quad * 4 + reg;
            float inv = __builtin_amdgcn_rcpf(fmaxf(den[m], EPS_));
            float ssum = 0.0f;
#pragma unroll
            for (int j = 0; j < 8; j++) {
                int n = n0 + j * 16 + lx;
                float u = acc[i][j][reg] * inv;
                Ub[(size_t)m * 512 + n] = f2b(u);
                ssum += u * u;
            }
            for (int o = 8; o; o >>= 1) ssum += __shfl_xor(ssum, o, 64);
            if (lx == 0) atomicAdd(&ssU[m], ssum);
        }
}

// ---------------- output projection split-K over 8 head-chunks (grid y MUST be 16) ----------------
__global__ __launch_bounds__(256, 2) void k_gemm_sk(const ushort* __restrict__ Ub,
                                                    const ushort* __restrict__ WoT,
                                                    float* __restrict__ Cp) {
    __shared__ ushort sh[GC_SH];
    int z = blockIdx.z;
    int m0 = blockIdx.y * 256, n0 = blockIdx.x * 128;
    int bb = m0 >> 10, s0 = m0 & 1023;
    const ushort* A = Ub + ((size_t)(bb * H_ + z) * S_ + s0) * 512;
    const ushort* BT = WoT + (size_t)z * 512;
    float* C = Cp + (size_t)z * 4096 * 512;
    f32x4 acc[4][8];
    gemm_core256(A, BT, 512, 4096, 512, 0, n0, sh, acc);
    int tid = threadIdx.x, w = tid >> 6, lane = tid & 63;
    int quad = lane >> 4, lx = lane & 15;
#pragma unroll
    for (int i = 0; i < 4; i++)
#pragma unroll
        for (int reg = 0; reg < 4; reg++) {
            int m = m0 + w * 64 + i * 16 + quad * 4 + reg;
#pragma unroll
            for (int j = 0; j < 8; j++) {
                int n = n0 + j * 16 + lx;
                C[(size_t)m * 512 + n] = acc[i][j][reg];
            }
        }
}

// ---------------- final reduce + in-block hyper factors + expmap ----------------
__global__ __launch_bounds__(256) void k_final_reduce_expmap(const float* __restrict__ Cp,
                                                             const float* __restrict__ ssU,
                                                             const float* __restrict__ bo,
                                                             float* __restrict__ out) {
    __shared__ float sm[24];
    int r = blockIdx.x;
    int b = r >> 10, s = r & 1023;
    if (threadIdx.x < 8) {
        int h = threadIdx.x;
        float ss = ssU[(size_t)(b * H_ + h) * S_ + s];
        float n = sqrtf(fmaxf(ss, EPS_));
        float a = 0.5f * atanhf(fminf(n, MAXT));
        float f1 = tanhf(a) / n;
        float mss = f1 * f1 * ss;
        float nm = sqrtf(fmaxf(mss, EPS_));
        float f2 = atanhf(fminf(nm, MAXT)) / nm;
        float f12 = f1 * f2;
        sm[h] = f12;
        sm[8 + h] = f12 * f12 * ss;
    }
    __syncthreads();
    if (threadIdx.x == 0) {
        float sum = 0.0f;
#pragma unroll
        for (int h = 0; h < 8; h++) sum += sm[8 + h];
        float nc = sqrtf(fmaxf(sum, EPS_));
        float f3 = tanhf(nc) / nc;
        float css = f3 * f3 * sum;
        float nc2 = sqrtf(fmaxf(css, EPS_));
        float f4 = atanhf(fminf(nc2, MAXT)) / nc2;
        sm[16] = f3 * f4;
    }
    __syncthreads();
    float g = sm[16];
    float a8[8];
#pragma unroll
    for (int z = 0; z < 8; z++) a8[z] = sm[z] * g;
    float v0 = bo[threadIdx.x], v1 = bo[threadIdx.x + 256];
#pragma unroll
    for (int z = 0; z < 8; z++) {
        const float* row = Cp + ((size_t)z * 4096 + r) * 512;
        v0 += a8[z] * row[threadIdx.x];
        v1 += a8[z] * row[threadIdx.x + 256];
    }
    float ss = blk_reduce_sum(v0 * v0 + v1 * v1, sm + 17);
    float n = sqrtf(fmaxf(ss, EPS_));
    float f = tanhf(n) / n;
    float* o = out + (size_t)r * D_;
    o[threadIdx.x] = f * v0;
    o[threadIdx.x + 256] = f * v1;
}

// ---------------- logmap0 rows -> bf16 tangent ----------------
__global__ __launch_bounds__(256) void k_logmap_bf16(const float* __restrict__ q,
                                                     const float* __restrict__ k,
                                                     const float* __restrict__ v,
                                                     ushort* __restrict__ tq,
                                                     ushort* __restrict__ tk,
                                                     ushort* __restrict__ tv) {
    __shared__ float sm[8];
    const float* x = (blockIdx.y == 0) ? q : (blockIdx.y == 1) ? k : v;
    ushort* t = (blockIdx.y == 0) ? tq : (blockIdx.y == 1) ? tk : tv;
    int r = blockIdx.x;
    const float* xr = x + (size_t)r * D_;
    float v0 = xr[threadIdx.x], v1 = xr[threadIdx.x + 256];
    float ss = blk_reduce_sum(v0 * v0 + v1 * v1, sm);
    float n = sqrtf(fmaxf(ss, EPS_));
    float f = atanhf(fminf(n, MAXT)) / n;
    ushort* tr = t + (size_t)r * D_;
    tr[threadIdx.x] = f2b(f * v0);
    tr[threadIdx.x + 256] = f2b(f * v1);
}

// ---------------- ALL weight transposes (z: 0=Wk, 1=Wv, 2..9=Wq heads, 10..17=Wo slices) ----------------
__global__ __launch_bounds__(256) void k_transpose_all(const float* __restrict__ Wk,
                                                       const float* __restrict__ Wv,
                                                       const float* __restrict__ Wq,
                                                       const float* __restrict__ Wo,
                                                       ushort* __restrict__ WkT,
                                                       ushort* __restrict__ WvT,
                                                       ushort* __restrict__ WqT,
                                                       ushort* __restrict__ WoT) {
    __shared__ float t[32][33];
    int z = blockIdx.z;
    int c0 = blockIdx.x * 32, r0 = blockIdx.y * 32;
    int tx = threadIdx.x & 31, ty = threadIdx.x >> 5;
    if (z < 10) {
        const float* in;
        ushort* out;
        if (z == 0) { in = Wk; out = WkT; }
        else if (z == 1) { in = Wv; out = WvT; }
        else { in = Wq + (size_t)(z - 2) * 512 * 512; out = WqT + (size_t)(z - 2) * 512 * 512; }
        for (int rr = ty; rr < 32; rr += 8) t[rr][tx] = in[(size_t)(r0 + rr) * 512 + c0 + tx];
        __syncthreads();
        for (int rr = ty; rr < 32; rr += 8)
            out[(size_t)(c0 + rr) * 512 + r0 + tx] = f2b(t[tx][rr]);
    } else {
        int zz = z - 10;
        const float* in = Wo + (size_t)zz * 512 * 512;
        for (int rr = ty; rr < 32; rr += 8) t[rr][tx] = in[(size_t)(r0 + rr) * 512 + c0 + tx];
        __syncthreads();
        for (int rr = ty; rr < 32; rr += 8)
            WoT[(size_t)(c0 + rr) * 4096 + zz * 512 + r0 + tx] = f2b(t[tx][rr]);
    }
}

extern "C" void kernel_launch(void* const* d_in, const int* in_sizes, int n_in,
                              void* d_out, int out_size, void* d_ws, size_t ws_size,
                              hipStream_t stream) {
    (void)in_sizes; (void)n_in; (void)out_size; (void)ws_size;
    const float* query = (const float*)d_in[0];
    const float* key = (const float*)d_in[1];
    const float* value = (const float*)d_in[2];
    const float* Wq = (const float*)d_in[3];
    const float* bq = (const float*)d_in[4];
    const float* Wk = (const float*)d_in[5];
    const float* bk = (const float*)d_in[6];
    const float* Wv = (const float*)d_in[7];
    const float* bv = (const float*)d_in[8];
    const float* Wo = (const float*)d_in[9];
    const float* bo = (const float*)d_in[10];
    const float* stau = (const float*)d_in[11];
    float* out = (float*)d_out;

    char* p = (char*)d_ws;
    auto alloc = [&](size_t bytes) {
        char* r = p;
        p += (bytes + 255) & ~(size_t)255;
        return r;
    };
    ushort* tq = (ushort*)alloc((size_t)4096 * 512 * 2);
    ushort* tk = (ushort*)alloc((size_t)4096 * 512 * 2);
    ushort* tv = (ushort*)alloc((size_t)4096 * 512 * 2);
    ushort* WqT = (ushort*)alloc((size_t)8 * 512 * 512 * 2);
    ushort* WkT = (ushort*)alloc((size_t)512 * 512 * 2);
    ushort* WvT = (ushort*)alloc((size_t)512 * 512 * 2);
    ushort* WoT = (ushort*)alloc((size_t)4096 * 512 * 2);
    ushort* yq = (ushort*)alloc((size_t)32768 * 512 * 2);
    ushort* yk = (ushort*)alloc((size_t)4096 * 512 * 2);
    ushort* yv = (ushort*)alloc((size_t)4096 * 512 * 2);
    ushort* yvT = (ushort*)alloc((size_t)4 * 512 * 1024 * 2);
    ushort* Ub = (ushort*)alloc((size_t)32768 * 512 * 2);
    ushort* Sc = (ushort*)alloc((size_t)4 * 8192 * 1024 * 2);  // alias: Cp after attnv consumes E
    float* den = (float*)alloc(32768 * 4);
    float* ssU = (float*)alloc(32768 * 4);
    float* ssq = (float*)alloc(32768 * 4);
    float* ssk = (float*)alloc(4096 * 4);
    float* ssv = (float*)alloc(4096 * 4);
    float* fq = (float*)alloc(32768 * 4);
    float* qn2 = (float*)alloc(32768 * 4);
    float* fk = (float*)alloc(4096 * 4);
    float* kn2 = (float*)alloc(4096 * 4);
    float* cv = (float*)alloc(4096 * 4);
    float* dsc = (float*)alloc(4096 * 4);
    float* Cp = (float*)Sc;

    hipMemsetAsync(den, 0, (size_t)(32768 * 3 + 4096 * 2 + 192) * 4, stream);

    // 1. tangent inputs (bf16)
    k_logmap_bf16<<<dim3(4096, 3), 256, 0, stream>>>(query, key, value, tq, tk, tv);

    // 2. all weight transposes, one launch
    k_transpose_all<<<dim3(16, 16, 18), 256, 0, stream>>>(Wk, Wv, Wq, Wo, WkT, WvT, WqT, WoT);

    // 3. all projections + per-row |y|^2 atomics (256-tiles: M=4096 -> y=16)
    k_gemm_proj_all<<<dim3(4, 16, 10), 256, 0, stream>>>(tq, tk, tv, WqT, WkT, WvT, bq, bk, bv,
                                                         yq, yk, yv, ssq, ssk, ssv);

    // 4. merged: yv transpose + ball factors
    k_post_proj<<<2208, 256, 0, stream>>>(yv, yvT, ssq, ssk, ssv, fq, qn2, fk, kn2, cv, dsc);

    // 5. attention (n-fastest grid mapping; M=8192 -> y=32)
    k_gemm_score<<<dim3(8, 32, 4), 256, 0, stream>>>(yq, yk, Sc, den, fq, qn2, fk, kn2, cv, dsc,
                                                     stau);
    k_gemm_attnv<<<dim3(4, 32, 4), 256, 0, stream>>>(Sc, yvT, den, Ub, ssU);

    // 6. output projection split-K (M=4096 -> y=16!) + fused factors/reduce/expmap
    k_gemm_sk<<<dim3(4, 16, 8), 256, 0, stream>>>(Ub, WoT, Cp);
    k_final_reduce_expmap<<<4096, 256, 0, stream>>>(Cp, ssU, bo, out);
}